// Round 14
// baseline (860.970 us; speedup 1.0000x reference)
//
#include <hip/hip_runtime.h>
#include <hip/hip_fp16.h>

// Problem constants (from reference)
constexpr int N_NODES = 100000;
constexpr int N_EDGES = 1600000;
constexpr int D = 64;          // D_IN == D_OUT == 64

constexpr int NCNTB  = 800;                                   // bin-hist blocks
constexpr int EPB2   = N_EDGES / NCNTB;                       // 2000 (exact)
constexpr int NCVT   = (N_NODES * D / 4) / 256;               // 6250 cvt blocks
constexpr int BINSH  = 9;                                     // 512-node coarse bins
constexpr int BINSZ  = 1 << BINSH;                            // 512
constexpr int NBINS  = (N_NODES + BINSZ - 1) >> BINSH;        // 196
constexpr int CHUNK  = 2048;                                  // pass-A edges per block
constexpr int NPA    = (N_EDGES + CHUNK - 1) / CHUNK;         // 782 pass-A blocks
constexpr int SUBN   = 128;                                   // k_agg sub-bin nodes
constexpr int NAGG   = NBINS * 4;                             // 784 agg blocks

// ---------------------------------------------------------------------------
// Workspace layout (bytes). Total 25,636,864 <= 40,280,064.
// Bin-sorted edges only (no node-level sort): k_agg scatters into LDS f32
// accumulators, so entries2/nstart/k_sortbin are eliminated.
// ---------------------------------------------------------------------------
constexpr size_t OFF_BINCNT   = 0;                             // NBINS ints
constexpr size_t OFF_BINSTART = 1024;                          // NBINS+1 ints
constexpr size_t OFF_BINCUR   = 2048;                          // NBINS ints
constexpr size_t OFF_W16      = 4096;                          // 32 KB (hi+lo planes)
constexpr size_t OFF_FEAT16   = 36864;                         // N_NODES*64 fp16
constexpr size_t OFF_ENTA     = OFF_FEAT16 + (size_t)N_NODES * D * 2;  // 12,836,864
constexpr size_t WS_NEEDED    = OFF_ENTA + (size_t)N_EDGES * 8;        // 25,636,864

typedef short  bf16x8 __attribute__((ext_vector_type(8)));
typedef float  f32x4  __attribute__((ext_vector_type(4)));

__device__ __forceinline__ unsigned short f2bf(float f) {   // RNE f32 -> bf16
    unsigned u = __float_as_uint(f);
    u += 0x7fffu + ((u >> 16) & 1u);
    return (unsigned short)(u >> 16);
}

// fp16 unpack helpers (gather path: 11-bit mantissa)
__device__ __forceinline__ float h2f_lo(unsigned u) {
    return __half2float(__ushort_as_half((unsigned short)(u & 0xFFFFu)));
}
__device__ __forceinline__ float h2f_hi(unsigned u) {
    return __half2float(__ushort_as_half((unsigned short)(u >> 16)));
}

// Split 8 consecutive f32 into hi/lo bf16 fragments (hi = RNE(f), lo = RNE(f - hi)).
__device__ __forceinline__ void split8(float4 p0, float4 p1, bf16x8& hi, bf16x8& lo) {
    float f[8] = {p0.x, p0.y, p0.z, p0.w, p1.x, p1.y, p1.z, p1.w};
#pragma unroll
    for (int i = 0; i < 8; ++i) {
        const unsigned short h = f2bf(f[i]);
        const float hf = __uint_as_float((unsigned)h << 16);
        hi[i] = (short)h;
        lo[i] = (short)f2bf(f[i] - hf);
    }
}

__device__ __forceinline__ float4 scale4(float4 v, float s) {
    return make_float4(v.x * s, v.y * s, v.z * s, v.w * s);
}

// ---------------------------------------------------------------------------
// K0: zero the per-bin counters (ws is poisoned before every launch).
// ---------------------------------------------------------------------------
__global__ __launch_bounds__(256) void k_zero(int* __restrict__ bincnt) {
    int i = blockIdx.x * 256 + threadIdx.x;
    if (i < NBINS) bincnt[i] = 0;
}

// ---------------------------------------------------------------------------
// K1 (fused): blocks [0,NCVT) convert feat f32->fp16; [NCVT,NCVT+NCNTB)
// LDS bin-level histogram (196 counters) -> global bincnt; last block builds
// combined W16 hi plane [j][k] (k<64=W_self, k>=64=W_neigh) AND lo plane.
// ---------------------------------------------------------------------------
__global__ __launch_bounds__(256) void k_pre(const float4* __restrict__ feat4,
                                             unsigned short* __restrict__ feat16,
                                             const float* __restrict__ Wn,
                                             const float* __restrict__ Ws,
                                             unsigned short* __restrict__ W16,
                                             const int* __restrict__ dst,
                                             int* __restrict__ bincnt) {
    __shared__ int l[NBINS];
    const int b   = blockIdx.x;
    const int tid = threadIdx.x;
    if (b < NCVT) {
        const int i = b * 256 + tid;
        float4 v = feat4[i];
        ushort4 o;
        o.x = __half_as_ushort(__float2half_rn(v.x));
        o.y = __half_as_ushort(__float2half_rn(v.y));
        o.z = __half_as_ushort(__float2half_rn(v.z));
        o.w = __half_as_ushort(__float2half_rn(v.w));
        *(ushort4*)&feat16[(size_t)i * 4] = o;
    } else if (b < NCVT + NCNTB) {
        for (int i = tid; i < NBINS; i += 256) l[i] = 0;
        __syncthreads();
        const int base = (b - NCVT) * EPB2;
        for (int k = tid; k < EPB2; k += 256)
            atomicAdd(&l[dst[base + k] >> BINSH], 1);
        __syncthreads();
        for (int i = tid; i < NBINS; i += 256)
            if (l[i]) atomicAdd(&bincnt[i], l[i]);
    } else {
        for (int e = tid; e < D * 128; e += 256) {
            const int j = e >> 7, k = e & 127;
            const float w = (k < D) ? Ws[j * D + k] : Wn[j * D + (k - D)];
            const unsigned short h = f2bf(w);
            const float hf = __uint_as_float((unsigned)h << 16);
            W16[e] = h;
            W16[D * 128 + e] = f2bf(w - hf);
        }
    }
}

// ---------------------------------------------------------------------------
// K2bin: exclusive scan of 196 bin counts -> binstart (+sentinel), bincur.
// ---------------------------------------------------------------------------
__global__ __launch_bounds__(256) void k_scan_bins(const int* __restrict__ bincnt,
                                                   int* __restrict__ binstart,
                                                   int* __restrict__ bincur) {
    __shared__ int s[256];
    const int t = threadIdx.x;
    const int v = (t < NBINS) ? bincnt[t] : 0;
    s[t] = v;
    __syncthreads();
    for (int off = 1; off < 256; off <<= 1) {
        int u = (t >= off) ? s[t - off] : 0;
        __syncthreads();
        s[t] += u;
        __syncthreads();
    }
    if (t < NBINS) { binstart[t] = s[t] - v; bincur[t] = s[t] - v; }
    if (t == 0) binstart[NBINS] = N_EDGES;
}

// ---------------------------------------------------------------------------
// K3: LDS-staged partition of edges into 196 coarse bins (512 dst nodes each)
// — unchanged from R11 (proven). entriesA.x = src | (dst&511)<<17.
// ---------------------------------------------------------------------------
__global__ __launch_bounds__(256) void k_place_a(const int* __restrict__ src,
                                                 const int* __restrict__ dst,
                                                 const float* __restrict__ ew,
                                                 int* __restrict__ bincur,
                                                 uint2* __restrict__ entriesA) {
    __shared__ __align__(16) uint2 stage[CHUNK];       // 16 KB
    __shared__ unsigned char sbin[CHUNK];              // 2 KB (bin < 196 fits)
    __shared__ int hist[NBINS], lstart[NBINS], lcur[NBINS], gbase[NBINS];
    __shared__ int s[256];
    const int tid = threadIdx.x;
    const int e0  = blockIdx.x * CHUNK;
    const int cnt = min(CHUNK, N_EDGES - e0);

    for (int i = tid; i < NBINS; i += 256) hist[i] = 0;
    __syncthreads();
    for (int k = tid; k < cnt; k += 256)
        atomicAdd(&hist[dst[e0 + k] >> BINSH], 1);
    __syncthreads();
    {
        const int v = (tid < NBINS) ? hist[tid] : 0;
        s[tid] = v;
        __syncthreads();
        for (int off = 1; off < 256; off <<= 1) {
            int u = (tid >= off) ? s[tid - off] : 0;
            __syncthreads();
            s[tid] += u;
            __syncthreads();
        }
        if (tid < NBINS) {
            const int ex = s[tid] - v;
            lstart[tid] = ex;
            lcur[tid]   = ex;
            gbase[tid]  = v ? atomicAdd(&bincur[tid], v) : 0;
        }
    }
    __syncthreads();
    for (int k = tid; k < cnt; k += 256) {
        const int d = dst[e0 + k];
        const int b = d >> BINSH;
        const int p = atomicAdd(&lcur[b], 1);
        stage[p] = make_uint2((unsigned)src[e0 + k] | ((unsigned)(d & (BINSZ - 1)) << 17),
                              __float_as_uint(ew[e0 + k]));
        sbin[p]  = (unsigned char)b;
    }
    __syncthreads();
    for (int j = tid; j < cnt; j += 256) {
        const int b = sbin[j];
        entriesA[gbase[b] + (j - lstart[b])] = stage[j];
    }
}

// ---------------------------------------------------------------------------
// K4 (fused scatter-aggregate + MFMA finalize): 4 blocks per 512-bin,
// each owning a 128-node sub-bin. Edges need only BIN order: each 16-lane
// group reads one entry (broadcast), filters sub-bin, gathers the 128B fp16
// row, and scatters 4 f32 LDS atomicAdds per lane. Every edge independent ->
// no per-node latency chains (R8-R11's measured bottleneck). deg via LDS
// histogram; mean-divide folded into P5 fragment load. Replaces k_sortbin +
// entries2 + nstart entirely.
// ---------------------------------------------------------------------------
__global__ __launch_bounds__(256, 4) void k_agg(
    const uint2* __restrict__ feat16u2,
    const float* __restrict__ feat32,
    const int* __restrict__ binstart,
    const uint2* __restrict__ entriesA,
    const unsigned short* __restrict__ W16,
    const float* __restrict__ bias,
    float* __restrict__ out) {
    __shared__ __align__(16) float aggrow[SUBN * 68];   // 34.8 KB f32
    __shared__ int deg[SUBN];
    const int tid  = threadIdx.x;
    const int b512 = blockIdx.x >> 2;
    const unsigned q = blockIdx.x & 3;
    const int s0   = binstart[b512];
    const int cnt  = binstart[b512 + 1] - s0;

    // zero accumulators
    for (int i = tid; i < SUBN * 68 / 4; i += 256)
        ((float4*)aggrow)[i] = make_float4(0.f, 0.f, 0.f, 0.f);
    if (tid < SUBN) deg[tid] = 0;
    __syncthreads();

    // scatter-aggregate: group g (16 lanes) takes entries g, g+16, ... of the
    // 512-bin slice; processes those in sub-bin q. x2 pair for gather MLP.
    const int g = tid >> 4, gl = tid & 15;
    int i = g;
    for (; i + 16 < cnt; i += 32) {
        const uint2 a0 = entriesA[s0 + i];
        const uint2 a1 = entriesA[s0 + i + 16];
        const bool m0 = ((a0.x >> 24) & 3u) == q;
        const bool m1 = ((a1.x >> 24) & 3u) == q;
        uint2 p0, p1;
        if (m0) p0 = feat16u2[(size_t)(a0.x & 0x1FFFFu) * 16 + gl];
        if (m1) p1 = feat16u2[(size_t)(a1.x & 0x1FFFFu) * 16 + gl];
        if (m0) {
            const float w = __uint_as_float(a0.y);
            float* r = &aggrow[(int)((a0.x >> 17) & 127u) * 68 + gl * 4];
            atomicAdd(r + 0, h2f_lo(p0.x) * w);
            atomicAdd(r + 1, h2f_hi(p0.x) * w);
            atomicAdd(r + 2, h2f_lo(p0.y) * w);
            atomicAdd(r + 3, h2f_hi(p0.y) * w);
            if (gl == 0) atomicAdd(&deg[(a0.x >> 17) & 127u], 1);
        }
        if (m1) {
            const float w = __uint_as_float(a1.y);
            float* r = &aggrow[(int)((a1.x >> 17) & 127u) * 68 + gl * 4];
            atomicAdd(r + 0, h2f_lo(p1.x) * w);
            atomicAdd(r + 1, h2f_hi(p1.x) * w);
            atomicAdd(r + 2, h2f_lo(p1.y) * w);
            atomicAdd(r + 3, h2f_hi(p1.y) * w);
            if (gl == 0) atomicAdd(&deg[(a1.x >> 17) & 127u], 1);
        }
    }
    for (; i < cnt; i += 16) {
        const uint2 a = entriesA[s0 + i];
        if (((a.x >> 24) & 3u) == q) {
            const uint2 p = feat16u2[(size_t)(a.x & 0x1FFFFu) * 16 + gl];
            const float w = __uint_as_float(a.y);
            float* r = &aggrow[(int)((a.x >> 17) & 127u) * 68 + gl * 4];
            atomicAdd(r + 0, h2f_lo(p.x) * w);
            atomicAdd(r + 1, h2f_hi(p.x) * w);
            atomicAdd(r + 2, h2f_lo(p.y) * w);
            atomicAdd(r + 3, h2f_hi(p.y) * w);
            if (gl == 0) atomicAdd(&deg[(a.x >> 17) & 127u], 1);
        }
    }
    __syncthreads();

    // P5: MFMA finalize, hi/lo split operands; mean-divide folded into the
    // aggrow fragment load. 4 waves x 2 row-tiles = 128 rows.
    const int wave = tid >> 6, lane = tid & 63;
    const int quad = lane >> 4, r = lane & 15;
    const int nbase = b512 * 512 + (int)q * SUBN;
    const unsigned short* W16lo = W16 + D * 128;

#pragma unroll
    for (int rti = 0; rti < 2; ++rti) {
        const int rt = wave * 2 + rti;
        const int node0 = nbase + rt * 16;
        int arow = node0 + r;
        if (arow > N_NODES - 1) arow = N_NODES - 1;

        bf16x8 ahi[4], alo[4];
        {
            const float* fp = &feat32[(size_t)arow * 64 + quad * 8];
            split8(*(const float4*)fp,        *(const float4*)(fp + 4),  ahi[0], alo[0]);
            split8(*(const float4*)(fp + 32), *(const float4*)(fp + 36), ahi[1], alo[1]);
            const int lrow = rt * 16 + r;
            const float inv = 1.0f / fmaxf((float)deg[lrow], 1.0f);
            const float* ap = &aggrow[lrow * 68 + quad * 8];
            split8(scale4(*(const float4*)ap,        inv),
                   scale4(*(const float4*)(ap + 4),  inv), ahi[2], alo[2]);
            split8(scale4(*(const float4*)(ap + 32), inv),
                   scale4(*(const float4*)(ap + 36), inv), ahi[3], alo[3]);
        }

        f32x4 acc4[4] = {};
#pragma unroll
        for (int nt = 0; nt < 4; ++nt) {
#pragma unroll
            for (int kc = 0; kc < 4; ++kc) {
                const size_t wo = (size_t)(nt * 16 + r) * 128 + kc * 32 + quad * 8;
                const bf16x8 bhi = *(const bf16x8*)&W16[wo];
                const bf16x8 blo = *(const bf16x8*)&W16lo[wo];
                acc4[nt] = __builtin_amdgcn_mfma_f32_16x16x32_bf16(ahi[kc], bhi, acc4[nt], 0, 0, 0);
                acc4[nt] = __builtin_amdgcn_mfma_f32_16x16x32_bf16(alo[kc], bhi, acc4[nt], 0, 0, 0);
                acc4[nt] = __builtin_amdgcn_mfma_f32_16x16x32_bf16(ahi[kc], blo, acc4[nt], 0, 0, 0);
            }
        }

#pragma unroll
        for (int nt = 0; nt < 4; ++nt) {
            const float bv = bias[nt * 16 + r];
#pragma unroll
            for (int reg = 0; reg < 4; ++reg) {
                const int m = node0 + quad * 4 + reg;
                if (m < N_NODES) out[(size_t)m * 64 + nt * 16 + r] = acc4[nt][reg] + bv;
            }
        }
    }
}

// ---------------------------------------------------------------------------
// Fallback path (R1): atomic scatter + shuffle finalize, if ws is too small.
// ---------------------------------------------------------------------------
__global__ __launch_bounds__(256) void fb_zero(float4* __restrict__ out4,
                                               float* __restrict__ deg) {
    const int stride = gridDim.x * blockDim.x;
    int i = blockIdx.x * blockDim.x + threadIdx.x;
    const int total4 = (N_NODES * D) / 4;
    for (int idx = i; idx < total4; idx += stride)
        out4[idx] = make_float4(0.f, 0.f, 0.f, 0.f);
    for (int idx = i; idx < N_NODES; idx += stride)
        deg[idx] = 0.f;
}

__global__ __launch_bounds__(256) void fb_scatter(
    const float* __restrict__ feat, const int* __restrict__ src,
    const int* __restrict__ dst, const float* __restrict__ ew,
    float* __restrict__ out, float* __restrict__ deg) {
    const int gid  = blockIdx.x * blockDim.x + threadIdx.x;
    const int e    = gid >> 6;
    const int lane = gid & 63;
    if (e >= N_EDGES) return;
    atomicAdd(&out[(size_t)dst[e] * D + lane], feat[(size_t)src[e] * D + lane] * ew[e]);
    if (lane == 0) atomicAdd(&deg[dst[e]], 1.0f);
}

__global__ __launch_bounds__(256) void fb_finalize(
    const float* __restrict__ feat, const float* __restrict__ Wn,
    const float* __restrict__ Ws, const float* __restrict__ bias,
    const float* __restrict__ deg, float* __restrict__ out) {
    __shared__ float lWn[D * 65];
    __shared__ float lWs[D * 65];
    for (int idx = threadIdx.x; idx < D * D; idx += 256) {
        const int r = idx >> 6, c = idx & 63;
        lWn[r * 65 + c] = Wn[idx];
        lWs[r * 65 + c] = Ws[idx];
    }
    __syncthreads();
    const int wave = threadIdx.x >> 6;
    const int lane = threadIdx.x & 63;
    const int n = blockIdx.x * 4 + wave;
    if (n >= N_NODES) return;
    const float f  = feat[(size_t)n * D + lane];
    const float sv = out[(size_t)n * D + lane];
    const float inv = 1.0f / fmaxf(deg[n], 1.0f);
    float acc_s = 0.f, acc_n = 0.f;
#pragma unroll
    for (int k = 0; k < D; ++k) {
        acc_s += __shfl(f, k)  * lWs[lane * 65 + k];
        acc_n += __shfl(sv, k) * lWn[lane * 65 + k];
    }
    out[(size_t)n * D + lane] = acc_s + acc_n * inv + bias[lane];
}

// ---------------------------------------------------------------------------
extern "C" void kernel_launch(void* const* d_in, const int* in_sizes, int n_in,
                              void* d_out, int out_size, void* d_ws, size_t ws_size,
                              hipStream_t stream) {
    const float* feat = (const float*)d_in[0];
    const int*   src  = (const int*)  d_in[1];
    const int*   dst  = (const int*)  d_in[2];
    const float* ew   = (const float*)d_in[3];
    const float* Wn   = (const float*)d_in[4];
    const float* Ws   = (const float*)d_in[5];
    const float* bias = (const float*)d_in[6];
    float* out = (float*)d_out;
    char* ws = (char*)d_ws;

    if (ws_size >= WS_NEEDED) {
        int* bincnt   = (int*)(ws + OFF_BINCNT);
        int* binstart = (int*)(ws + OFF_BINSTART);
        int* bincur   = (int*)(ws + OFF_BINCUR);
        unsigned short* W16    = (unsigned short*)(ws + OFF_W16);
        unsigned short* feat16 = (unsigned short*)(ws + OFF_FEAT16);
        uint2* entriesA = (uint2*)(ws + OFF_ENTA);

        k_zero     <<<1, 256, 0, stream>>>(bincnt);
        k_pre      <<<NCVT + NCNTB + 1, 256, 0, stream>>>((const float4*)feat, feat16,
                                                          Wn, Ws, W16, dst, bincnt);
        k_scan_bins<<<1, 256, 0, stream>>>(bincnt, binstart, bincur);
        k_place_a  <<<NPA, 256, 0, stream>>>(src, dst, ew, bincur, entriesA);
        k_agg      <<<NAGG, 256, 0, stream>>>((const uint2*)feat16, feat, binstart,
                                              entriesA, W16, bias, out);
    } else {
        float* deg = (float*)d_ws;
        fb_zero<<<2048, 256, 0, stream>>>((float4*)out, deg);
        fb_scatter<<<(N_EDGES * 64) / 256, 256, 0, stream>>>(feat, src, dst, ew, out, deg);
        fb_finalize<<<(N_NODES + 3) / 4, 256, 0, stream>>>(feat, Wn, Ws, bias, deg, out);
    }
}

// Round 15
// 234.553 us; speedup vs baseline: 3.6707x; 3.6707x over previous
//
#include <hip/hip_runtime.h>
#include <hip/hip_fp16.h>

// Problem constants (from reference)
constexpr int N_NODES = 100000;
constexpr int N_EDGES = 1600000;
constexpr int D = 64;          // D_IN == D_OUT == 64

// Bucketing: 64 consecutive dst nodes per bucket (one k_bucket block each).
constexpr int BSH    = 6;
constexpr int BN     = 1 << BSH;                              // 64
constexpr int NBUCK  = (N_NODES + BN - 1) / BN;               // 1563
constexpr int NN3    = NBUCK * BN;                            // 100032 (padded)
constexpr int NCNTB  = 800;                                   // bin-hist blocks
constexpr int EPB2   = N_EDGES / NCNTB;                       // 2000 (exact)
constexpr int NCVT   = (N_NODES * D / 4) / 256;               // 6250 cvt blocks
constexpr int BINSH  = 9;                                     // 512-node coarse bins
constexpr int BINSZ  = 1 << BINSH;                            // 512
constexpr int NBINS  = (NN3 + BINSZ - 1) >> BINSH;            // 196
constexpr int CHUNK  = 2048;                                  // pass-A edges per block
constexpr int NPA    = (N_EDGES + CHUNK - 1) / CHUNK;         // 782 pass-A blocks

// ---------------------------------------------------------------------------
// Workspace layout (bytes). Total 40,035,844 <= 40,280,064.
// R8 k_bucket (best measured: 75.6us) + R11 preprocessing (196 bins).
// ---------------------------------------------------------------------------
constexpr size_t OFF_NSTART   = 0;                             // NN3+1 ints
constexpr size_t OFF_BINCNT   = 400384;                        // NBINS ints
constexpr size_t OFF_BINSTART = 401408;                        // NBINS+1 ints
constexpr size_t OFF_BINCUR   = 402432;                        // NBINS ints
constexpr size_t OFF_W16      = 403456;                        // 32 KB (hi+lo planes)
constexpr size_t OFF_FEAT16   = 436224;                        // N_NODES*64 fp16
constexpr size_t OFF_ENT2     = OFF_FEAT16 + (size_t)N_NODES * D * 2;  // 13,236,224
constexpr size_t OFF_ENTA     = OFF_ENT2 + (size_t)N_EDGES * 8;        // 26,036,224
constexpr size_t WS_NEEDED    = OFF_ENTA + (size_t)N_EDGES * 8;        // 38,836,224

typedef short  bf16x8 __attribute__((ext_vector_type(8)));
typedef float  f32x4  __attribute__((ext_vector_type(4)));

__device__ __forceinline__ unsigned short f2bf(float f) {   // RNE f32 -> bf16
    unsigned u = __float_as_uint(f);
    u += 0x7fffu + ((u >> 16) & 1u);
    return (unsigned short)(u >> 16);
}

// fp16 unpack helpers (gather path: 11-bit mantissa)
__device__ __forceinline__ float h2f_lo(unsigned u) {
    return __half2float(__ushort_as_half((unsigned short)(u & 0xFFFFu)));
}
__device__ __forceinline__ float h2f_hi(unsigned u) {
    return __half2float(__ushort_as_half((unsigned short)(u >> 16)));
}

// Split 8 consecutive f32 into hi/lo bf16 fragments (hi = RNE(f), lo = RNE(f - hi)).
__device__ __forceinline__ void split8(float4 p0, float4 p1, bf16x8& hi, bf16x8& lo) {
    float f[8] = {p0.x, p0.y, p0.z, p0.w, p1.x, p1.y, p1.z, p1.w};
#pragma unroll
    for (int i = 0; i < 8; ++i) {
        const unsigned short h = f2bf(f[i]);
        const float hf = __uint_as_float((unsigned)h << 16);
        hi[i] = (short)h;
        lo[i] = (short)f2bf(f[i] - hf);
    }
}

// ---------------------------------------------------------------------------
// K0: zero the per-bin counters (ws is poisoned before every launch).
// ---------------------------------------------------------------------------
__global__ __launch_bounds__(256) void k_zero(int* __restrict__ bincnt) {
    int i = blockIdx.x * 256 + threadIdx.x;
    if (i < NBINS) bincnt[i] = 0;
}

// ---------------------------------------------------------------------------
// K1 (fused): blocks [0,NCVT) convert feat f32->fp16; [NCVT,NCVT+NCNTB)
// LDS bin-level histogram (196 counters) -> global bincnt; last block builds
// combined W16 hi plane [j][k] (k<64=W_self, k>=64=W_neigh) AND lo plane.
// ---------------------------------------------------------------------------
__global__ __launch_bounds__(256) void k_pre(const float4* __restrict__ feat4,
                                             unsigned short* __restrict__ feat16,
                                             const float* __restrict__ Wn,
                                             const float* __restrict__ Ws,
                                             unsigned short* __restrict__ W16,
                                             const int* __restrict__ dst,
                                             int* __restrict__ bincnt) {
    __shared__ int l[NBINS];
    const int b   = blockIdx.x;
    const int tid = threadIdx.x;
    if (b < NCVT) {
        const int i = b * 256 + tid;
        float4 v = feat4[i];
        ushort4 o;
        o.x = __half_as_ushort(__float2half_rn(v.x));
        o.y = __half_as_ushort(__float2half_rn(v.y));
        o.z = __half_as_ushort(__float2half_rn(v.z));
        o.w = __half_as_ushort(__float2half_rn(v.w));
        *(ushort4*)&feat16[(size_t)i * 4] = o;
    } else if (b < NCVT + NCNTB) {
        for (int i = tid; i < NBINS; i += 256) l[i] = 0;
        __syncthreads();
        const int base = (b - NCVT) * EPB2;
        for (int k = tid; k < EPB2; k += 256)
            atomicAdd(&l[dst[base + k] >> BINSH], 1);
        __syncthreads();
        for (int i = tid; i < NBINS; i += 256)
            if (l[i]) atomicAdd(&bincnt[i], l[i]);
    } else {
        for (int e = tid; e < D * 128; e += 256) {
            const int j = e >> 7, k = e & 127;
            const float w = (k < D) ? Ws[j * D + k] : Wn[j * D + (k - D)];
            const unsigned short h = f2bf(w);
            const float hf = __uint_as_float((unsigned)h << 16);
            W16[e] = h;
            W16[D * 128 + e] = f2bf(w - hf);
        }
    }
}

// ---------------------------------------------------------------------------
// K2bin: exclusive scan of 196 bin counts -> binstart (+sentinel), bincur.
// ---------------------------------------------------------------------------
__global__ __launch_bounds__(256) void k_scan_bins(const int* __restrict__ bincnt,
                                                   int* __restrict__ binstart,
                                                   int* __restrict__ bincur) {
    __shared__ int s[256];
    const int t = threadIdx.x;
    const int v = (t < NBINS) ? bincnt[t] : 0;
    s[t] = v;
    __syncthreads();
    for (int off = 1; off < 256; off <<= 1) {
        int u = (t >= off) ? s[t - off] : 0;
        __syncthreads();
        s[t] += u;
        __syncthreads();
    }
    if (t < NBINS) { binstart[t] = s[t] - v; bincur[t] = s[t] - v; }
    if (t == 0) binstart[NBINS] = N_EDGES;
}

// ---------------------------------------------------------------------------
// K3a: LDS-staged partition of edges into 196 coarse bins (512 dst nodes
// each) — R11-proven. entriesA.x = src | (dst&511)<<17.
// ---------------------------------------------------------------------------
__global__ __launch_bounds__(256) void k_place_a(const int* __restrict__ src,
                                                 const int* __restrict__ dst,
                                                 const float* __restrict__ ew,
                                                 int* __restrict__ bincur,
                                                 uint2* __restrict__ entriesA) {
    __shared__ __align__(16) uint2 stage[CHUNK];       // 16 KB
    __shared__ unsigned char sbin[CHUNK];              // 2 KB (bin < 196 fits)
    __shared__ int hist[NBINS], lstart[NBINS], lcur[NBINS], gbase[NBINS];
    __shared__ int s[256];
    const int tid = threadIdx.x;
    const int e0  = blockIdx.x * CHUNK;
    const int cnt = min(CHUNK, N_EDGES - e0);

    for (int i = tid; i < NBINS; i += 256) hist[i] = 0;
    __syncthreads();
    for (int k = tid; k < cnt; k += 256)
        atomicAdd(&hist[dst[e0 + k] >> BINSH], 1);
    __syncthreads();
    {
        const int v = (tid < NBINS) ? hist[tid] : 0;
        s[tid] = v;
        __syncthreads();
        for (int off = 1; off < 256; off <<= 1) {
            int u = (tid >= off) ? s[tid - off] : 0;
            __syncthreads();
            s[tid] += u;
            __syncthreads();
        }
        if (tid < NBINS) {
            const int ex = s[tid] - v;
            lstart[tid] = ex;
            lcur[tid]   = ex;
            gbase[tid]  = v ? atomicAdd(&bincur[tid], v) : 0;
        }
    }
    __syncthreads();
    for (int k = tid; k < cnt; k += 256) {
        const int d = dst[e0 + k];
        const int b = d >> BINSH;
        const int p = atomicAdd(&lcur[b], 1);
        stage[p] = make_uint2((unsigned)src[e0 + k] | ((unsigned)(d & (BINSZ - 1)) << 17),
                              __float_as_uint(ew[e0 + k]));
        sbin[p]  = (unsigned char)b;
    }
    __syncthreads();
    for (int j = tid; j < cnt; j += 256) {
        const int b = sbin[j];
        entriesA[gbase[b] + (j - lstart[b])] = stage[j];
    }
}

// ---------------------------------------------------------------------------
// K3b (fused sort): one 1024-thread block per 512-node bin (196 blocks).
// Histogram -> in-block scan -> nstart -> node-sorted placement. Padded
// nodes (100000..100031) have zero counts, so their scan positions equal
// the bin end (= N_EDGES for the last bin) — valid sentinels for k_bucket.
// ---------------------------------------------------------------------------
__global__ __launch_bounds__(1024) void k_sortbin(const int* __restrict__ binstart,
                                                  const uint2* __restrict__ entriesA,
                                                  int* __restrict__ nstart,
                                                  uint2* __restrict__ entries2) {
    __shared__ int h[BINSZ];
    __shared__ int sc[BINSZ];
    __shared__ int cur[BINSZ];
    const int tid = threadIdx.x;
    const int b   = blockIdx.x;
    const int s0  = binstart[b];
    const int cnt = binstart[b + 1] - s0;

    if (tid < BINSZ) h[tid] = 0;
    __syncthreads();
    for (int k = tid; k < cnt; k += 1024)
        atomicAdd(&h[entriesA[s0 + k].x >> 17], 1);
    __syncthreads();
    // in-block exclusive scan of the 512 per-node counts (first 512 threads)
    const int v = (tid < BINSZ) ? h[tid] : 0;
    if (tid < BINSZ) sc[tid] = v;
    __syncthreads();
    for (int off = 1; off < BINSZ; off <<= 1) {
        int u = 0;
        if (tid < BINSZ && tid >= off) u = sc[tid - off];
        __syncthreads();
        if (tid < BINSZ) sc[tid] += u;
        __syncthreads();
    }
    if (tid < BINSZ) {
        const int pos = s0 + sc[tid] - v;    // absolute start of this node's run
        cur[tid] = pos;
        const int n = (b << BINSH) + tid;
        if (n < NN3) nstart[n] = pos;        // pad nodes get bin end (=N_EDGES last bin)
    }
    if (b == NBINS - 1 && tid == 0) nstart[NN3] = N_EDGES;
    __syncthreads();
    // place: bin slice is L2-warm from the histogram pass
    for (int k = tid; k < cnt; k += 1024) {
        const uint2 a = entriesA[s0 + k];
        const int p = atomicAdd(&cur[a.x >> 17], 1);
        entries2[p] = make_uint2(a.x & 0x1FFFFu, a.y);
    }
}

// ---------------------------------------------------------------------------
// K4 (aggregate + MFMA finalize): EXACT R8 structure (best measured 75.6us;
// R11's BN=32 and R14's LDS-scatter both regressed). BN=64, x2 unroll,
// fp16 gather, f32 aggrow, split-bf16 MFMA.
// ---------------------------------------------------------------------------
__global__ __launch_bounds__(256, 8) void k_bucket(
    const uint2* __restrict__ feat16u2,
    const float* __restrict__ feat32,
    const int* __restrict__ nstart,
    const uint2* __restrict__ entries2,
    const unsigned short* __restrict__ W16,
    const float* __restrict__ bias,
    float* __restrict__ out) {
    __shared__ __align__(16) float aggrow[BN * 68];   // 17.4 KB f32
    __shared__ int hh[BN], st[BN];
    const int tid = threadIdx.x;
    const int b   = blockIdx.x;

    if (tid < BN) {
        const int s = nstart[b * BN + tid];
        const int e = nstart[b * BN + tid + 1];
        st[tid] = s;
        hh[tid] = e - s;
    }
    __syncthreads();

    // P4: aggregate — single acc, 4 lane-groups, stride 4, unroll x2.
    const int wave = tid >> 6, lane = tid & 63;
    const int group = lane >> 4, gl = lane & 15;
    for (int t = 0; t < 16; ++t) {
        const int dl  = wave * 16 + t;
        const int ss  = st[dl];
        const int deg = hh[dl];
        const int se  = ss + deg;
        float4 acc = make_float4(0.f, 0.f, 0.f, 0.f);
        int e = ss + group;
        for (; e + 4 < se; e += 8) {
            const uint2 en0 = entries2[e];
            const uint2 en1 = entries2[e + 4];
            const uint2 p0  = feat16u2[(size_t)en0.x * 16 + gl];
            const uint2 p1  = feat16u2[(size_t)en1.x * 16 + gl];
            const float w0  = __uint_as_float(en0.y);
            const float w1  = __uint_as_float(en1.y);
            acc.x = fmaf(h2f_lo(p0.x), w0, acc.x);
            acc.y = fmaf(h2f_hi(p0.x), w0, acc.y);
            acc.z = fmaf(h2f_lo(p0.y), w0, acc.z);
            acc.w = fmaf(h2f_hi(p0.y), w0, acc.w);
            acc.x = fmaf(h2f_lo(p1.x), w1, acc.x);
            acc.y = fmaf(h2f_hi(p1.x), w1, acc.y);
            acc.z = fmaf(h2f_lo(p1.y), w1, acc.z);
            acc.w = fmaf(h2f_hi(p1.y), w1, acc.w);
        }
        if (e < se) {
            const uint2 en = entries2[e];
            const float w  = __uint_as_float(en.y);
            const uint2 p  = feat16u2[(size_t)en.x * 16 + gl];
            acc.x = fmaf(h2f_lo(p.x), w, acc.x);
            acc.y = fmaf(h2f_hi(p.x), w, acc.y);
            acc.z = fmaf(h2f_lo(p.y), w, acc.z);
            acc.w = fmaf(h2f_hi(p.y), w, acc.w);
        }
#pragma unroll
        for (int m = 16; m <= 32; m <<= 1) {
            acc.x += __shfl_xor(acc.x, m);
            acc.y += __shfl_xor(acc.y, m);
            acc.z += __shfl_xor(acc.z, m);
            acc.w += __shfl_xor(acc.w, m);
        }
        if (group == 0) {
            const float inv = 1.0f / fmaxf((float)deg, 1.0f);
            float4 o = make_float4(acc.x * inv, acc.y * inv, acc.z * inv, acc.w * inv);
            *(float4*)&aggrow[dl * 68 + gl * 4] = o;
        }
    }
    __syncthreads();

    // P5: MFMA finalize with hi/lo split operands (near-f32 numerics).
    const int quad = lane >> 4, r = lane & 15;
    const int node0 = b * BN + wave * 16;
    int arow = node0 + r;
    if (arow > N_NODES - 1) arow = N_NODES - 1;

    bf16x8 ahi[4], alo[4];
    {
        const float* fp = &feat32[(size_t)arow * 64 + quad * 8];
        split8(*(const float4*)fp,        *(const float4*)(fp + 4),  ahi[0], alo[0]);
        split8(*(const float4*)(fp + 32), *(const float4*)(fp + 36), ahi[1], alo[1]);
        const float* ap = &aggrow[(wave * 16 + r) * 68 + quad * 8];
        split8(*(const float4*)ap,        *(const float4*)(ap + 4),  ahi[2], alo[2]);
        split8(*(const float4*)(ap + 32), *(const float4*)(ap + 36), ahi[3], alo[3]);
    }

    const unsigned short* W16lo = W16 + D * 128;
    f32x4 acc4[4] = {};
#pragma unroll
    for (int nt = 0; nt < 4; ++nt) {
#pragma unroll
        for (int kc = 0; kc < 4; ++kc) {
            const size_t wo = (size_t)(nt * 16 + r) * 128 + kc * 32 + quad * 8;
            const bf16x8 bhi = *(const bf16x8*)&W16[wo];
            const bf16x8 blo = *(const bf16x8*)&W16lo[wo];
            acc4[nt] = __builtin_amdgcn_mfma_f32_16x16x32_bf16(ahi[kc], bhi, acc4[nt], 0, 0, 0);
            acc4[nt] = __builtin_amdgcn_mfma_f32_16x16x32_bf16(alo[kc], bhi, acc4[nt], 0, 0, 0);
            acc4[nt] = __builtin_amdgcn_mfma_f32_16x16x32_bf16(ahi[kc], blo, acc4[nt], 0, 0, 0);
        }
    }

#pragma unroll
    for (int nt = 0; nt < 4; ++nt) {
        const float bv = bias[nt * 16 + r];
#pragma unroll
        for (int reg = 0; reg < 4; ++reg) {
            const int m = node0 + quad * 4 + reg;
            if (m < N_NODES) out[(size_t)m * 64 + nt * 16 + r] = acc4[nt][reg] + bv;
        }
    }
}

// ---------------------------------------------------------------------------
// Fallback path (R1): atomic scatter + shuffle finalize, if ws is too small.
// ---------------------------------------------------------------------------
__global__ __launch_bounds__(256) void fb_zero(float4* __restrict__ out4,
                                               float* __restrict__ deg) {
    const int stride = gridDim.x * blockDim.x;
    int i = blockIdx.x * blockDim.x + threadIdx.x;
    const int total4 = (N_NODES * D) / 4;
    for (int idx = i; idx < total4; idx += stride)
        out4[idx] = make_float4(0.f, 0.f, 0.f, 0.f);
    for (int idx = i; idx < N_NODES; idx += stride)
        deg[idx] = 0.f;
}

__global__ __launch_bounds__(256) void fb_scatter(
    const float* __restrict__ feat, const int* __restrict__ src,
    const int* __restrict__ dst, const float* __restrict__ ew,
    float* __restrict__ out, float* __restrict__ deg) {
    const int gid  = blockIdx.x * blockDim.x + threadIdx.x;
    const int e    = gid >> 6;
    const int lane = gid & 63;
    if (e >= N_EDGES) return;
    atomicAdd(&out[(size_t)dst[e] * D + lane], feat[(size_t)src[e] * D + lane] * ew[e]);
    if (lane == 0) atomicAdd(&deg[dst[e]], 1.0f);
}

__global__ __launch_bounds__(256) void fb_finalize(
    const float* __restrict__ feat, const float* __restrict__ Wn,
    const float* __restrict__ Ws, const float* __restrict__ bias,
    const float* __restrict__ deg, float* __restrict__ out) {
    __shared__ float lWn[D * 65];
    __shared__ float lWs[D * 65];
    for (int idx = threadIdx.x; idx < D * D; idx += 256) {
        const int r = idx >> 6, c = idx & 63;
        lWn[r * 65 + c] = Wn[idx];
        lWs[r * 65 + c] = Ws[idx];
    }
    __syncthreads();
    const int wave = threadIdx.x >> 6;
    const int lane = threadIdx.x & 63;
    const int n = blockIdx.x * 4 + wave;
    if (n >= N_NODES) return;
    const float f  = feat[(size_t)n * D + lane];
    const float sv = out[(size_t)n * D + lane];
    const float inv = 1.0f / fmaxf(deg[n], 1.0f);
    float acc_s = 0.f, acc_n = 0.f;
#pragma unroll
    for (int k = 0; k < D; ++k) {
        acc_s += __shfl(f, k)  * lWs[lane * 65 + k];
        acc_n += __shfl(sv, k) * lWn[lane * 65 + k];
    }
    out[(size_t)n * D + lane] = acc_s + acc_n * inv + bias[lane];
}

// ---------------------------------------------------------------------------
extern "C" void kernel_launch(void* const* d_in, const int* in_sizes, int n_in,
                              void* d_out, int out_size, void* d_ws, size_t ws_size,
                              hipStream_t stream) {
    const float* feat = (const float*)d_in[0];
    const int*   src  = (const int*)  d_in[1];
    const int*   dst  = (const int*)  d_in[2];
    const float* ew   = (const float*)d_in[3];
    const float* Wn   = (const float*)d_in[4];
    const float* Ws   = (const float*)d_in[5];
    const float* bias = (const float*)d_in[6];
    float* out = (float*)d_out;
    char* ws = (char*)d_ws;

    if (ws_size >= WS_NEEDED) {
        int* nstart   = (int*)(ws + OFF_NSTART);
        int* bincnt   = (int*)(ws + OFF_BINCNT);
        int* binstart = (int*)(ws + OFF_BINSTART);
        int* bincur   = (int*)(ws + OFF_BINCUR);
        unsigned short* W16    = (unsigned short*)(ws + OFF_W16);
        unsigned short* feat16 = (unsigned short*)(ws + OFF_FEAT16);
        uint2* entries2 = (uint2*)(ws + OFF_ENT2);
        uint2* entriesA = (uint2*)(ws + OFF_ENTA);

        k_zero     <<<1, 256, 0, stream>>>(bincnt);
        k_pre      <<<NCVT + NCNTB + 1, 256, 0, stream>>>((const float4*)feat, feat16,
                                                          Wn, Ws, W16, dst, bincnt);
        k_scan_bins<<<1, 256, 0, stream>>>(bincnt, binstart, bincur);
        k_place_a  <<<NPA, 256, 0, stream>>>(src, dst, ew, bincur, entriesA);
        k_sortbin  <<<NBINS, 1024, 0, stream>>>(binstart, entriesA, nstart, entries2);
        k_bucket   <<<NBUCK, 256, 0, stream>>>((const uint2*)feat16, feat, nstart,
                                               entries2, W16, bias, out);
    } else {
        float* deg = (float*)d_ws;
        fb_zero<<<2048, 256, 0, stream>>>((float4*)out, deg);
        fb_scatter<<<(N_EDGES * 64) / 256, 256, 0, stream>>>(feat, src, dst, ew, out, deg);
        fb_finalize<<<(N_NODES + 3) / 4, 256, 0, stream>>>(feat, Wn, Ws, bias, deg, out);
    }
}